// Round 4
// baseline (388.108 us; speedup 1.0000x reference)
//
#include <hip/hip_runtime.h>
#include <math.h>

#define NN 8
#define CC 256
#define HH 112
#define WW 112
#define MIP 8
#define EPS 1e-5f
#define NBLK 512             // 2 blocks/CU on 256 CUs -> guaranteed co-resident (capacity 4/CU)
#define NREP 4               // NBLK*NREP = 2048 planes / items
#define NPOS (NN * HH)       // 896 positions per branch

typedef float nvec4 __attribute__((ext_vector_type(4)));

// Self-resetting grid barrier state (load-time zero init; sense-reversing
// protocol leaves cnt==0 after each use, gen monotonically increases across
// graph replays -> no per-launch reset needed).
__device__ int g_cnt = 0;
__device__ int g_gen = 0;

__device__ __forceinline__ void grid_barrier() {
    __syncthreads();
    if (threadIdx.x == 0) {
        __threadfence();   // release: all prior global writes visible device-wide
        // ACQUIRE: must not sink past the fetch_add below, else we could
        // observe a gen advanced by our own barrier and spin on the next one.
        const int my_gen = __hip_atomic_load(&g_gen, __ATOMIC_ACQUIRE,
                                             __HIP_MEMORY_SCOPE_AGENT);
        const int prev = __hip_atomic_fetch_add(&g_cnt, 1, __ATOMIC_ACQ_REL,
                                                __HIP_MEMORY_SCOPE_AGENT);
        if (prev == NBLK - 1) {
            __hip_atomic_store(&g_cnt, 0, __ATOMIC_RELAXED,
                               __HIP_MEMORY_SCOPE_AGENT);
            __hip_atomic_fetch_add(&g_gen, 1, __ATOMIC_RELEASE,
                                   __HIP_MEMORY_SCOPE_AGENT);
        } else {
            int spins = 0;
            while (__hip_atomic_load(&g_gen, __ATOMIC_ACQUIRE,
                                     __HIP_MEMORY_SCOPE_AGENT) == my_gen) {
                __builtin_amdgcn_s_sleep(2);
                if (++spins > (1 << 22)) break;   // safety valve: no hangs
            }
        }
        __threadfence();   // acquire: other blocks' writes visible to us
    }
    __syncthreads();
}

// Pooled/attention buffer layout (position-major, channel-contiguous):
//   branch 0 (h-pool): P[((n*HH + h)*CC + c)]
//   branch 1 (w-pool): P[NN*HH*CC + ((n*WW + w)*CC + c)]
__global__ __launch_bounds__(256, 4) void fused_kernel(
    const float* __restrict__ x,
    const float* __restrict__ bn1_g, const float* __restrict__ bn1_b,
    const float* __restrict__ bn1_m, const float* __restrict__ bn1_v,
    const float* __restrict__ bn2_g, const float* __restrict__ bn2_b,
    const float* __restrict__ bn2_m, const float* __restrict__ bn2_v,
    const float* __restrict__ ds_w, const float* __restrict__ ds_b,
    const float* __restrict__ us_w, const float* __restrict__ us_b,
    float* __restrict__ pool, float* __restrict__ out) {
    const int t = threadIdx.x;

    __shared__ union {
        struct { float rowpart[HH][29]; float4 colpart[8][28]; } p1;  // 16.2 KB
        struct { float s[CC]; float dsh[MIP]; } p2;
        struct { float ah[HH]; float aw[WW]; } p3;
    } sm;

    // ------------------------- Phase 1: dual-axis pooling -------------------
#pragma unroll 1
    for (int rep = 0; rep < NREP; ++rep) {
        const int b = blockIdx.x + rep * NBLK;     // 0..2047 = n*CC + c
        const int n = b / CC;
        const int c = b % CC;
        const nvec4* p4 = (const nvec4*)(x + (size_t)b * (HH * WW));

        if (t < 224) {
            const int g = t / 28;                  // row group 0..7
            const int j = t % 28;                  // float4 column 0..27
            float4 ca = make_float4(0.f, 0.f, 0.f, 0.f);
#pragma unroll
            for (int k = 0; k < 14; ++k) {
                const int r = g + 8 * k;
                nvec4 v = __builtin_nontemporal_load(&p4[r * 28 + j]);
                ca.x += v.x; ca.y += v.y; ca.z += v.z; ca.w += v.w;
                sm.p1.rowpart[r][j] = v.x + v.y + v.z + v.w;
            }
            sm.p1.colpart[g][j] = ca;
        }
        __syncthreads();

        if (t < HH) {
            float s = 0.f;
#pragma unroll
            for (int j = 0; j < 28; ++j) s += sm.p1.rowpart[t][j];
            pool[((size_t)(n * HH + t)) * CC + c] = s * (1.0f / WW);
        } else if (t < 112 + WW) {
            const int w = t - 112;
            const float* cp = (const float*)&sm.p1.colpart[0][0];  // [8][112]
            float s = 0.f;
#pragma unroll
            for (int g = 0; g < 8; ++g) s += cp[g * 112 + w];
            pool[(size_t)(NN * HH * CC) + ((size_t)(n * WW + w)) * CC + c] =
                s * (1.0f / HH);
        }
        __syncthreads();   // LDS reuse fence before next rep
    }
    grid_barrier();

    // --------------- Phase 2: BN -> C->MIP relu -> MIP->C sigmoid ----------
#pragma unroll 1
    for (int rep = 0; rep < NREP; ++rep) {
        const int item = blockIdx.x + rep * NBLK;  // 0..2047, valid < 1792
        const bool active = item < 2 * NPOS;
        const int it = active ? item : 0;          // inactive blocks shadow item 0
        const int branch = it >= NPOS;
        const int pos = it - branch * NPOS;
        const int c = t;

        const float* g  = branch ? bn2_g : bn1_g;
        const float* be = branch ? bn2_b : bn1_b;
        const float* mn = branch ? bn2_m : bn1_m;
        const float* vr = branch ? bn2_v : bn1_v;

        const size_t idx =
            (size_t)branch * (NN * HH * CC) + (size_t)pos * CC + c;

        const float v = pool[idx];
        const float scale = g[c] * rsqrtf(vr[c] + EPS);
        const float vb = v * scale + (be[c] - mn[c] * scale);
        sm.p2.s[c] = vb;
        __syncthreads();

        {
            const int grp = c >> 5;
            const int l = c & 31;
            float partial = 0.f;
#pragma unroll
            for (int k = 0; k < CC / 32; ++k) {
                const int cc = l + k * 32;
                partial += ds_w[grp * CC + cc] * sm.p2.s[cc];
            }
#pragma unroll
            for (int off = 16; off > 0; off >>= 1)
                partial += __shfl_down(partial, off, 32);
            if (l == 0) sm.p2.dsh[grp] = fmaxf(partial + ds_b[grp], 0.f);
        }
        __syncthreads();

        float acc = us_b[c];
#pragma unroll
        for (int m = 0; m < MIP; ++m) acc += us_w[c * MIP + m] * sm.p2.dsh[m];
        if (active) pool[idx] = 1.0f / (1.0f + expf(-acc));
        __syncthreads();   // LDS reuse fence before next rep
    }
    grid_barrier();

    // ------------------------- Phase 3: apply + h-swish ---------------------
#pragma unroll 1
    for (int rep = 0; rep < NREP; ++rep) {
        const int b = blockIdx.x + rep * NBLK;     // 0..2047 = n*CC + c
        const int n = b / CC;
        const int c = b % CC;

        if (t < HH) {
            sm.p3.ah[t] = pool[((size_t)(n * HH + t)) * CC + c];
        } else if (t >= 128 && t < 128 + WW) {
            const int w = t - 128;
            sm.p3.aw[w] =
                pool[(size_t)(NN * HH * CC) + ((size_t)(n * WW + w)) * CC + c];
        }
        __syncthreads();

        const nvec4* xp = (const nvec4*)(x + (size_t)b * (HH * WW));
        nvec4* op = (nvec4*)(out + (size_t)b * (HH * WW));
#pragma unroll 4
        for (int i = t; i < HH * (WW / 4); i += 256) {
            const int h = i / (WW / 4);
            const int w4 = i % (WW / 4);
            nvec4 xv = __builtin_nontemporal_load(&xp[i]);
            const float a_h = sm.p3.ah[h];
            nvec4 o;
            o.x = xv.x * (sm.p3.aw[w4 * 4 + 0] * a_h) + xv.x;
            o.y = xv.y * (sm.p3.aw[w4 * 4 + 1] * a_h) + xv.y;
            o.z = xv.z * (sm.p3.aw[w4 * 4 + 2] * a_h) + xv.z;
            o.w = xv.w * (sm.p3.aw[w4 * 4 + 3] * a_h) + xv.w;
            nvec4 r;
            r.x = o.x * fminf(fmaxf(o.x + 3.0f, 0.0f), 6.0f) * (1.0f / 6.0f);
            r.y = o.y * fminf(fmaxf(o.y + 3.0f, 0.0f), 6.0f) * (1.0f / 6.0f);
            r.z = o.z * fminf(fmaxf(o.z + 3.0f, 0.0f), 6.0f) * (1.0f / 6.0f);
            r.w = o.w * fminf(fmaxf(o.w + 3.0f, 0.0f), 6.0f) * (1.0f / 6.0f);
            __builtin_nontemporal_store(r, &op[i]);
        }
        __syncthreads();   // LDS reuse fence before next rep
    }
}

extern "C" void kernel_launch(void* const* d_in, const int* in_sizes, int n_in,
                              void* d_out, int out_size, void* d_ws, size_t ws_size,
                              hipStream_t stream) {
    const float* x     = (const float*)d_in[0];
    const float* bn1_g = (const float*)d_in[1];
    const float* bn1_b = (const float*)d_in[2];
    const float* bn1_m = (const float*)d_in[3];
    const float* bn1_v = (const float*)d_in[4];
    const float* bn2_g = (const float*)d_in[5];
    const float* bn2_b = (const float*)d_in[6];
    const float* bn2_m = (const float*)d_in[7];
    const float* bn2_v = (const float*)d_in[8];
    const float* ds_w  = (const float*)d_in[9];
    const float* ds_b  = (const float*)d_in[10];
    const float* us_w  = (const float*)d_in[11];
    const float* us_b  = (const float*)d_in[12];
    float* out  = (float*)d_out;
    float* pool = (float*)d_ws;   // 2*N*112*C*4 = 1.75 MB

    fused_kernel<<<NBLK, 256, 0, stream>>>(x,
        bn1_g, bn1_b, bn1_m, bn1_v, bn2_g, bn2_b, bn2_m, bn2_v,
        ds_w, ds_b, us_w, us_b, pool, out);
}